// Round 1
// baseline (66.910 us; speedup 1.0000x reference)
//
#include <hip/hip_runtime.h>

#define N 4096
#define IN_F 256
#define OUT_F 64
#define HEADS 4
#define ALPHA 0.2f
#define RPW 8   // rows per wave in the h-GEMM

// ---------------------------------------------------------------------------
// K1: build hamilton[4][256][64] from W_heads[4][64][64]
// hamilton[q*64+kr][p*16+fr] = sign[q][p] * W[kr][comp[q][p]*16 + fr]
// ---------------------------------------------------------------------------
__global__ __launch_bounds__(256) void k_build_ham(const float* __restrict__ W,
                                                   float* __restrict__ ham) {
    int tid = blockIdx.x * 256 + threadIdx.x;          // 0..65535
    int hd = tid >> 14;
    int kk = (tid >> 6) & 255;
    int f  = tid & 63;
    int q = kk >> 6, kr = kk & 63;
    int p = f >> 4,  fr = f & 15;
    const int   comp_t[4][4] = {{0,1,2,3},{1,0,3,2},{2,3,0,1},{3,2,1,0}};
    const float sign_t[4][4] = {{1.f,-1.f,-1.f,-1.f},
                                {1.f, 1.f,-1.f, 1.f},
                                {1.f, 1.f, 1.f,-1.f},
                                {1.f,-1.f, 1.f, 1.f}};
    int   c = comp_t[q][p];
    float s = sign_t[q][p];
    ham[tid] = s * W[(hd * 64 + kr) * 64 + c * 16 + fr];
}

// ---------------------------------------------------------------------------
// K2: h[hd][i][f] = sum_k x[i][k] * ham[hd][k][f]   (fp32, vector ALU)
// block = 256 threads = 4 waves, wave == head; each wave does RPW rows,
// lane == feature. x loads are wave-uniform -> scalar loads (SMEM pipe).
// Fused: e_src/e_dst dot products via shuffle reduce.
// ---------------------------------------------------------------------------
__global__ __launch_bounds__(256) void k_hgemm(const float* __restrict__ x,
                                               const float* __restrict__ ham,
                                               const float* __restrict__ a,
                                               float* __restrict__ h,
                                               float* __restrict__ e_src_p,
                                               float* __restrict__ e_dst_p) {
    const int wave = threadIdx.x >> 6;
    const int lane = threadIdx.x & 63;
    const int hd   = wave;
    const int i0   = blockIdx.x * RPW;

    float acc[RPW];
#pragma unroll
    for (int r = 0; r < RPW; ++r) acc[r] = 0.f;

    const float* hamh = ham + hd * (IN_F * OUT_F);
    for (int k = 0; k < IN_F; k += 4) {
        const float hv0 = hamh[(k + 0) * OUT_F + lane];
        const float hv1 = hamh[(k + 1) * OUT_F + lane];
        const float hv2 = hamh[(k + 2) * OUT_F + lane];
        const float hv3 = hamh[(k + 3) * OUT_F + lane];
#pragma unroll
        for (int r = 0; r < RPW; ++r) {
            const float4 xv = *reinterpret_cast<const float4*>(&x[(i0 + r) * IN_F + k]);
            acc[r] = fmaf(xv.x, hv0, acc[r]);
            acc[r] = fmaf(xv.y, hv1, acc[r]);
            acc[r] = fmaf(xv.z, hv2, acc[r]);
            acc[r] = fmaf(xv.w, hv3, acc[r]);
        }
    }

    const float a_s = a[hd * 128 + lane];
    const float a_d = a[hd * 128 + 64 + lane];
#pragma unroll
    for (int r = 0; r < RPW; ++r) {
        h[(hd * N + i0 + r) * OUT_F + lane] = acc[r];
        float p = acc[r] * a_s;
        float q = acc[r] * a_d;
#pragma unroll
        for (int off = 32; off > 0; off >>= 1) {
            p += __shfl_xor(p, off);
            q += __shfl_xor(q, off);
        }
        if (lane == 0) {
            e_src_p[(i0 + r) * 4 + hd] = p;
            e_dst_p[(i0 + r) * 4 + hd] = q;
        }
    }
}

// ---------------------------------------------------------------------------
// K4: Dmax[hd] = max_j e_dst[hd][j]  (upper bound for shift-stable softmax)
// ---------------------------------------------------------------------------
__global__ __launch_bounds__(256) void k_dmax(const float* __restrict__ e_dst_p,
                                              float* __restrict__ Dmax) {
    __shared__ float sm[256];
    const int hd = blockIdx.x;
    float m = -3.0e38f;
    for (int j = threadIdx.x; j < N; j += 256)
        m = fmaxf(m, e_dst_p[j * 4 + hd]);
    sm[threadIdx.x] = m;
    __syncthreads();
    for (int s = 128; s > 0; s >>= 1) {
        if (threadIdx.x < s) sm[threadIdx.x] = fmaxf(sm[threadIdx.x], sm[threadIdx.x + s]);
        __syncthreads();
    }
    if (threadIdx.x == 0) Dmax[hd] = sm[0];
}

// ---------------------------------------------------------------------------
// K5: masked-softmax attention, single pass over adj.
// One wave per row i; lane == output feature. Scan adj[i][:] as float4,
// ballot the nonzeros, process each edge for all 4 heads.
// m[hd] = lrelu(e_src[i] + Dmax[hd]) >= every masked e -> exp() in (0,1].
// ---------------------------------------------------------------------------
__global__ __launch_bounds__(256) void k_attn(const float* __restrict__ adj,
                                              const float* __restrict__ h,
                                              const float* __restrict__ e_src_p,
                                              const float* __restrict__ e_dst_p,
                                              const float* __restrict__ Dmax,
                                              float* __restrict__ out) {
    const int wave = threadIdx.x >> 6;
    const int lane = threadIdx.x & 63;
    const int i = blockIdx.x * 4 + wave;

    const float4 es4 = *reinterpret_cast<const float4*>(&e_src_p[i * 4]);
    const float es[4] = {es4.x, es4.y, es4.z, es4.w};
    float m[4], lsum[4], acc[4];
#pragma unroll
    for (int hd = 0; hd < 4; ++hd) {
        const float t = es[hd] + Dmax[hd];
        m[hd] = t > 0.f ? t : ALPHA * t;
        lsum[hd] = 0.f;
        acc[hd] = 0.f;
    }

    const float4* arow = reinterpret_cast<const float4*>(adj + (size_t)i * N);
    for (int t = 0; t < N / 256; ++t) {
        const float4 av = arow[t * 64 + lane];
#pragma unroll
        for (int s = 0; s < 4; ++s) {
            const float aval = (s == 0) ? av.x : (s == 1) ? av.y : (s == 2) ? av.z : av.w;
            unsigned long long mk = __ballot(aval > 0.f);
            while (mk) {
                const int b = __builtin_ctzll(mk);
                mk &= mk - 1;
                const int j = t * 256 + b * 4 + s;
                const float4 ed4 = *reinterpret_cast<const float4*>(&e_dst_p[j * 4]);
                const float edv[4] = {ed4.x, ed4.y, ed4.z, ed4.w};
#pragma unroll
                for (int hd = 0; hd < 4; ++hd) {
                    float z = es[hd] + edv[hd];
                    z = z > 0.f ? z : ALPHA * z;
                    const float w = __expf(z - m[hd]);
                    lsum[hd] += w;
                    acc[hd] = fmaf(w, h[(hd * N + j) * OUT_F + lane], acc[hd]);
                }
            }
        }
    }

#pragma unroll
    for (int hd = 0; hd < 4; ++hd) {
        const float v = acc[hd] / lsum[hd];
        out[i * 256 + hd * 64 + lane] = v > 0.f ? v : __expf(v) - 1.f;
    }
}

// ---------------------------------------------------------------------------
extern "C" void kernel_launch(void* const* d_in, const int* in_sizes, int n_in,
                              void* d_out, int out_size, void* d_ws, size_t ws_size,
                              hipStream_t stream) {
    const float* x   = (const float*)d_in[0];
    const float* adj = (const float*)d_in[1];
    const float* W   = (const float*)d_in[2];
    const float* a   = (const float*)d_in[3];
    float* out = (float*)d_out;

    float* ws      = (float*)d_ws;
    float* ham     = ws;                         // 4*256*64   = 65536 floats
    float* h       = ham + HEADS * IN_F * OUT_F; // 4*4096*64  = 1048576 floats
    float* e_src_p = h + HEADS * N * OUT_F;      // 4096*4
    float* e_dst_p = e_src_p + N * HEADS;        // 4096*4
    float* Dmax    = e_dst_p + N * HEADS;        // 4

    k_build_ham<<<256, 256, 0, stream>>>(W, ham);
    k_hgemm<<<N / RPW, 256, 0, stream>>>(x, ham, a, h, e_src_p, e_dst_p);
    k_dmax<<<HEADS, 256, 0, stream>>>(e_dst_p, Dmax);
    k_attn<<<N / 4, 256, 0, stream>>>(adj, h, e_src_p, e_dst_p, Dmax, out);
}